// Round 5
// baseline (88.531 us; speedup 1.0000x reference)
//
#include <hip/hip_runtime.h>

// B=8, M=12, N=32, D=256, C=1024, O=512, BM=96 (b*m rows).
//
// Algebraic collapse of GEMM1: ef is linear in the per-row sums S (32 vals):
//   ef[(n,k)] = (S_n + 2 S_k - (n==k) S_k)/512  =>  h = relu(W1A @ S),
//   W1A[o][n] = (sum_k W1[o][32n+k] + 2 sum_m W1[o][32m+n] - W1[o][33n])/512
// W1A is 512x32 (64 KB) -> GEMM1 becomes a per-bm GEMV that kB recomputes
// locally. Ht round-trip eliminated. 3 plain kernels, no device barriers
// (round 3/4 showed in-kernel group barriers cost ~9 us each vs 4.25 us
// per kernel boundary).
//
//   kA (44 blocks):  bid<32 -> W1A (16 o-rows each); bid>=32 -> Ssum (8 bm).
//   kB (16x12):      h = relu(W1A@S) local + GEMM2 + sigmoid -> Et.
//   kC (192):        stage x, local Ssum, gram (t<256, r0 mapping),
//                    mask(Et) + softmax + att@x -> out.
//
// ws (floats): W1A @0 (16384), Ssum @16384 (3072), Et @19456 (98304).

__device__ __forceinline__ float dot4(float4 a, float4 b) {
    return a.x*b.x + a.y*b.y + a.z*b.z + a.w*b.w;
}
__device__ __forceinline__ void fma4(float4& acc, float s, float4 v) {
    acc.x += s*v.x; acc.y += s*v.y; acc.z += s*v.z; acc.w += s*v.w;
}

// ---------------- kA: W1A reduction + Ssum ----------------------------------
__global__ __launch_bounds__(512) void kA(const float* __restrict__ x,
                                          const float* __restrict__ W1,
                                          float* __restrict__ W1A,
                                          float* __restrict__ Ssum) {
    __shared__ float w[16][1024];    // 64 KB (only used by W1A blocks)
    const int t = threadIdx.x, bid = blockIdx.x;
    if (bid < 32) {
        // stage 16 W1 rows (64 KB), fully coalesced
        const float4* W14 = (const float4*)(W1 + bid*16384);
        float4* w4 = (float4*)&w[0][0];
        #pragma unroll
        for (int i = 0; i < 8; ++i) w4[t + 512*i] = W14[t + 512*i];
        __syncthreads();
        const int ol = t >> 5, n = t & 31;   // 16 o-rows x 32 n-lanes
        const float* row = &w[ol][0];
        float T1 = 0.f, T2 = 0.f;
        // T1: contiguous chunk n, read order skewed by +n so lane banks differ
        #pragma unroll
        for (int k = 0; k < 32; ++k) T1 += row[n*32 + ((k + n) & 31)];
        // T2: column n across chunks; bank = n for every m -> conflict-free
        #pragma unroll
        for (int m = 0; m < 32; ++m) T2 += row[m*32 + n];
        float diag = row[n*33];
        W1A[(bid*16 + ol)*32 + n] = (T1 + 2.f*T2 - diag) * (1.f/512.f);
    } else {
        // Ssum for bm-group g = bid-32 (8 rows)
        const int g = bid - 32;
        const float4* x4 = (const float4*)x;
        const int n = t >> 4, dq = t & 15;   // 32 rows x 16 lanes
        #pragma unroll
        for (int bl = 0; bl < 8; ++bl) {
            const float4* xb = x4 + (g*8 + bl)*2048;
            float s = 0.f;
            #pragma unroll
            for (int j = 0; j < 4; ++j) {
                float4 v = xb[n*64 + dq + 16*j];
                s += v.x + v.y + v.z + v.w;
            }
            s += __shfl_xor(s, 1, 16);
            s += __shfl_xor(s, 2, 16);
            s += __shfl_xor(s, 4, 16);
            s += __shfl_xor(s, 8, 16);
            if (dq == 0) Ssum[(g*8 + bl)*32 + n] = s;
        }
    }
}

// ---------------- kB: h = relu(W1A@S) + GEMM2 + sigmoid -> Et ---------------
// grid (16 cQ, 12 g), 512 threads.
__global__ __launch_bounds__(512) void kB(const float* __restrict__ W1A,
                                          const float* __restrict__ Ssum,
                                          const float* __restrict__ W2,
                                          float* __restrict__ Et) {
    __shared__ float S_l[8][32];     // 1 KB
    __shared__ float hl[8][512];     // 16 KB
    const int t = threadIdx.x;
    const int cQ = blockIdx.x, g = blockIdx.y;
    if (t < 256) ((float*)S_l)[t] = Ssum[g*256 + t];
    __syncthreads();
    // h: thread t owns output column o = t for all 8 bm rows.
    {
        const float4* wa = (const float4*)(W1A + t*32);
        float4 w0=wa[0], w1=wa[1], w2=wa[2], w3=wa[3],
               w4=wa[4], w5=wa[5], w6=wa[6], w7=wa[7];
        #pragma unroll
        for (int bl = 0; bl < 8; ++bl) {
            const float4* s4 = (const float4*)&S_l[bl][0];   // broadcast reads
            float a = dot4(w0,s4[0]) + dot4(w1,s4[1]) + dot4(w2,s4[2]) +
                      dot4(w3,s4[3]) + dot4(w4,s4[4]) + dot4(w5,s4[5]) +
                      dot4(w6,s4[6]) + dot4(w7,s4[7]);
            hl[bl][t] = fmaxf(a, 0.f);      // bank = t%32, conflict-free
        }
    }
    __syncthreads();
    // GEMM2: 64 c's per block, 4 per thread; 32-lane K slices.
    const int olane = t & 31, cgp = t >> 5;   // cgp 0..15
    const int c0 = cQ*64 + cgp;
    const float4* w4a = (const float4*)(W2 + (c0     )*512);
    const float4* w4b = (const float4*)(W2 + (c0 + 16)*512);
    const float4* w4c = (const float4*)(W2 + (c0 + 32)*512);
    const float4* w4d = (const float4*)(W2 + (c0 + 48)*512);
    float accA[8] = {0.f,0.f,0.f,0.f,0.f,0.f,0.f,0.f};
    float accB[8] = {0.f,0.f,0.f,0.f,0.f,0.f,0.f,0.f};
    float accC[8] = {0.f,0.f,0.f,0.f,0.f,0.f,0.f,0.f};
    float accD[8] = {0.f,0.f,0.f,0.f,0.f,0.f,0.f,0.f};
    #pragma unroll
    for (int oo = 0; oo < 4; ++oo) {
        float4 hv[8];
        #pragma unroll
        for (int bl = 0; bl < 8; ++bl)
            hv[bl] = *((const float4*)&hl[bl][(oo*32 + olane)*4]);
        float4 wa = w4a[oo*32 + olane];
        float4 wb = w4b[oo*32 + olane];
        float4 wc = w4c[oo*32 + olane];
        float4 wd = w4d[oo*32 + olane];
        #pragma unroll
        for (int bl = 0; bl < 8; ++bl) {
            accA[bl] += dot4(wa, hv[bl]);
            accB[bl] += dot4(wb, hv[bl]);
            accC[bl] += dot4(wc, hv[bl]);
            accD[bl] += dot4(wd, hv[bl]);
        }
    }
    #pragma unroll
    for (int bl = 0; bl < 8; ++bl) {
        float a = accA[bl], b = accB[bl], c = accC[bl], d = accD[bl];
        #pragma unroll
        for (int m = 1; m < 32; m <<= 1) {
            a += __shfl_xor(a, m, 32);
            b += __shfl_xor(b, m, 32);
            c += __shfl_xor(c, m, 32);
            d += __shfl_xor(d, m, 32);
        }
        accA[bl]=a; accB[bl]=b; accC[bl]=c; accD[bl]=d;
    }
    if (olane == 0) {
        #pragma unroll
        for (int bl = 0; bl < 8; ++bl) {
            int row = (g*8 + bl)*1024;
            Et[row + c0]      = 1.f/(1.f + __expf(-accA[bl]));
            Et[row + c0 + 16] = 1.f/(1.f + __expf(-accB[bl]));
            Et[row + c0 + 32] = 1.f/(1.f + __expf(-accC[bl]));
            Et[row + c0 + 48] = 1.f/(1.f + __expf(-accD[bl]));
        }
    }
}

// ---------------- kC: gram + mask + softmax + att@x -------------------------
// grid 192 = 96 bm x 2 d-halves; 512 threads.
__global__ __launch_bounds__(512) void kC(const float* __restrict__ x,
                                          const float* __restrict__ Et,
                                          float* __restrict__ out) {
    __shared__ float4 xs4[32][65];      // pad 65 f4 (proven r0 pattern)
    __shared__ float att[32][36];
    __shared__ float S_l[32];
    const int t = threadIdx.x;
    const int bm = blockIdx.x >> 1, hh = blockIdx.x & 1;
    const float4* x4 = (const float4*)x;

    #pragma unroll
    for (int i = 0; i < 4; ++i) {
        int idx = t + 512*i;            // 0..2047
        xs4[idx >> 6][idx & 63] = x4[bm*2048 + idx];
    }
    __syncthreads();
    // local Ssum from staged tile
    {
        int r = t >> 4, dq = t & 15;
        float s = 0.f;
        #pragma unroll
        for (int j = 0; j < 4; ++j) {
            float4 v = xs4[r][dq + 16*j];
            s += v.x + v.y + v.z + v.w;
        }
        s += __shfl_xor(s, 1, 16);
        s += __shfl_xor(s, 2, 16);
        s += __shfl_xor(s, 4, 16);
        s += __shfl_xor(s, 8, 16);
        if (dq == 0) S_l[r] = s;
    }
    __syncthreads();
    // gram 2x2 on t<256 (r0 mapping -- conflict-profile proven); waves 4-7 idle
    if (t < 256) {
        int a = t >> 4, b = t & 15;
        float g00=0.f, g01=0.f, g10=0.f, g11=0.f;
        #pragma unroll 8
        for (int q = 0; q < 64; ++q) {
            float4 a0 = xs4[a][q],    a1 = xs4[a+16][q];
            float4 b0 = xs4[b][q],    b1 = xs4[b+16][q];
            g00 += dot4(a0,b0); g01 += dot4(a0,b1);
            g10 += dot4(a1,b0); g11 += dot4(a1,b1);
        }
        float sa0 = S_l[a]    * (1.f/256.f);
        float sa1 = S_l[a+16] * (1.f/256.f);
        float sb0 = S_l[b], sb1 = S_l[b+16];
        const float* Eb = Et + bm*1024;
        float e00 = Eb[a*32 + b];
        float e01 = Eb[a*32 + b+16];
        float e10 = Eb[(a+16)*32 + b];
        float e11 = Eb[(a+16)*32 + b+16];
        att[a][b]       = (g00 - sa0*sb0) > 0.f ? e00 : -1e12f;
        att[a][b+16]    = (g01 - sa0*sb1) > 0.f ? e01 : -1e12f;
        att[a+16][b]    = (g10 - sa1*sb0) > 0.f ? e10 : -1e12f;
        att[a+16][b+16] = (g11 - sa1*sb1) > 0.f ? e11 : -1e12f;
    }
    __syncthreads();
    // masked softmax per row: 32 rows x 16 lanes, 2 floats per lane
    {
        int r = t >> 4, q = t & 15;
        float2 lg = *((const float2*)&att[r][q*2]);
        float m = fmaxf(lg.x, lg.y);
        m = fmaxf(m, __shfl_xor(m,1,16));
        m = fmaxf(m, __shfl_xor(m,2,16));
        m = fmaxf(m, __shfl_xor(m,4,16));
        m = fmaxf(m, __shfl_xor(m,8,16));
        float2 p;
        p.x = __expf(lg.x-m); p.y = __expf(lg.y-m);
        float s = p.x + p.y;
        s += __shfl_xor(s,1,16);
        s += __shfl_xor(s,2,16);
        s += __shfl_xor(s,4,16);
        s += __shfl_xor(s,8,16);
        float inv = 1.f/s;
        p.x*=inv; p.y*=inv;
        *((float2*)&att[r][q*2]) = p;
    }
    __syncthreads();
    // out[r, d-half] = sum_k att[r,k] * x[k, d-half]; 2 rows per thread
    {
        int txl = t & 31, wy = t >> 5;   // 32 f4 cols x 16 row-groups
        int r0 = wy*2;
        float4 acc0={0,0,0,0}, acc1={0,0,0,0};
        #pragma unroll
        for (int kq = 0; kq < 8; ++kq) {
            float4 xa = xs4[kq*4+0][hh*32 + txl];
            float4 xb = xs4[kq*4+1][hh*32 + txl];
            float4 xc = xs4[kq*4+2][hh*32 + txl];
            float4 xd = xs4[kq*4+3][hh*32 + txl];
            float4 w0 = *((const float4*)&att[r0+0][kq*4]);
            float4 w1 = *((const float4*)&att[r0+1][kq*4]);
            fma4(acc0,w0.x,xa); fma4(acc0,w0.y,xb); fma4(acc0,w0.z,xc); fma4(acc0,w0.w,xd);
            fma4(acc1,w1.x,xa); fma4(acc1,w1.y,xb); fma4(acc1,w1.z,xc); fma4(acc1,w1.w,xd);
        }
        float4* out4 = (float4*)out;
        int base = bm*2048 + hh*32 + txl;
        out4[base + (r0+0)*64] = acc0;
        out4[base + (r0+1)*64] = acc1;
    }
}

extern "C" void kernel_launch(void* const* d_in, const int* in_sizes, int n_in,
                              void* d_out, int out_size, void* d_ws, size_t ws_size,
                              hipStream_t stream) {
    const float* x  = (const float*)d_in[0];
    const float* W1 = (const float*)d_in[1];
    const float* W2 = (const float*)d_in[2];
    float* out = (float*)d_out;
    float* ws  = (float*)d_ws;

    float* W1A  = ws;            // 16384 floats
    float* Ssum = ws + 16384;    // 3072 floats
    float* Et   = ws + 19456;    // 98304 floats

    kA<<<44, 512, 0, stream>>>(x, W1, W1A, Ssum);
    kB<<<dim3(16, 12), 512, 0, stream>>>(W1A, Ssum, W2, Et);
    kC<<<192, 512, 0, stream>>>(x, Et, out);
}

// Round 7
// 88.430 us; speedup vs baseline: 1.0011x; 1.0011x over previous
//
#include <hip/hip_runtime.h>

// B=8, M=12, N=32, D=256, C=1024, O=512, BM=96 (b*m rows).
//
// Single normal-launch kernel, grid 192 x 512. r5 algebraic collapse:
//   ef linear in row-sums S  =>  h = relu(W1A @ S),
//   W1A[o][n] = (sum_k W1[o][32n+k] + 2 sum_m W1[o][32m+n] - W1[o][33n])/512
// Every GROUP (16 blocks sharing g=bid>>4) computes the full W1A redundantly
// (block oT=bid&15 does 32 rows); cross-group duplicate writes are
// identical-value races (benign). Group-scoped arrive/spin barriers at agent
// scope (r3/r4-proven); cross-block data (W1A, Ssum, Et) via relaxed
// agent-scope atomics. Barrier counters in zero-init __device__ globals with
// last-of-16 self-reset.
//
// r7 fix vs r6: sa/sb mask scalars are loaded INSIDE the t<256 guard.
// r6 read S_loc[ga+16] with ga up to 31 (t>=256) -> OOB read of float[32],
// formal UB -> clang value-range propagation may assume t<256 for ALL
// threads and miscompile softmax/att@x index math. All indices now audited
// in-bounds for every t.
//
// Schedule:
//   P0 : stage x tile, local S, store S (hh==0), W1A slice   -> arrive bar0
//   P3b: gram + mask scalars -> regs (hides bar0)            -> wait bar0
//   P2 : h = relu(W1A@S) + GEMM2 + sigmoid -> Et             -> arrive bar1
//                                                            -> wait bar1
//   P3c: mask(Et) + softmax + att@x -> out
//
// ws (floats): W1A @0 (16384), Ssum @16384 (3072), Et @19456 (98304).

#define NGRP 12

__device__ unsigned int g_bar0[NGRP * 32];
__device__ unsigned int g_bar1[NGRP * 32];
__device__ unsigned int g_done[NGRP * 32];

__device__ __forceinline__ float dot4(float4 a, float4 b) {
    return a.x*b.x + a.y*b.y + a.z*b.z + a.w*b.w;
}
__device__ __forceinline__ void fma4(float4& acc, float s, float4 v) {
    acc.x += s*v.x; acc.y += s*v.y; acc.z += s*v.z; acc.w += s*v.w;
}

__device__ __forceinline__ void st_agent(float* p, float v) {
    __hip_atomic_store(p, v, __ATOMIC_RELAXED, __HIP_MEMORY_SCOPE_AGENT);
}
__device__ __forceinline__ float ld_agent(const float* p) {
    return __hip_atomic_load(p, __ATOMIC_RELAXED, __HIP_MEMORY_SCOPE_AGENT);
}
__device__ __forceinline__ unsigned long long ld_agent64(const unsigned long long* p) {
    return __hip_atomic_load(p, __ATOMIC_RELAXED, __HIP_MEMORY_SCOPE_AGENT);
}

// arrive: syncthreads drains all waves' stores (vmcnt 0 at barrier), then +1.
__device__ __forceinline__ void bar_arrive(unsigned int* ctr) {
    __syncthreads();
    if (threadIdx.x == 0)
        __hip_atomic_fetch_add(ctr, 1u, __ATOMIC_RELAXED, __HIP_MEMORY_SCOPE_AGENT);
}
__device__ __forceinline__ void bar_wait(unsigned int* ctr) {
    if (threadIdx.x == 0) {
        while (__hip_atomic_load(ctr, __ATOMIC_RELAXED, __HIP_MEMORY_SCOPE_AGENT) < 16u)
            __builtin_amdgcn_s_sleep(2);
    }
    __syncthreads();
}

__global__ __launch_bounds__(512) void fused(
        const float* __restrict__ x, const float* __restrict__ W1,
        const float* __restrict__ W2, float* __restrict__ out,
        float* __restrict__ W1A, float* __restrict__ Ssum,
        float* __restrict__ Et)
{
    __shared__ float4 xs4[32][65];      // 33280 B  (x tile, alive P0..end)
    __shared__ float  w[16][1024];      // 65536 B  (W1 stage, P0 only)
    __shared__ float  hl[8][512];       // 16384 B  (P2)
    __shared__ float  att[32][36];      //  4608 B  (P3c)
    __shared__ float  S_l8[8][32];      //  1024 B  (P2)
    __shared__ float  S_loc[32];        //   128 B  (P0..P3)
    const int t = threadIdx.x;
    const int bid = blockIdx.x;
    const int g = bid >> 4;             // bm-group 0..11
    const int gi = g * 32;
    const int bm = bid >> 1, hh = bid & 1;
    const float4* x4 = (const float4*)x;

    // ---------------- P0: stage x, local S, store S, W1A slice -------------
    #pragma unroll
    for (int i = 0; i < 4; ++i) {
        int idx = t + 512*i;            // 0..2047
        xs4[idx >> 6][idx & 63] = x4[bm*2048 + idx];
    }
    __syncthreads();
    {
        int r = t >> 4, dq = t & 15;
        float s = 0.f;
        #pragma unroll
        for (int j = 0; j < 4; ++j) {
            float4 v = xs4[r][dq + 16*j];
            s += v.x + v.y + v.z + v.w;
        }
        s += __shfl_xor(s, 1, 16);
        s += __shfl_xor(s, 2, 16);
        s += __shfl_xor(s, 4, 16);
        s += __shfl_xor(s, 8, 16);
        if (dq == 0) S_loc[r] = s;
    }
    __syncthreads();
    if (hh == 0 && t < 32) st_agent(&Ssum[bm*32 + t], S_loc[t]);
    // W1A slice: rows [oT*32, oT*32+32), staged 16 rows at a time (r5 kA)
    {
        const int oT = bid & 15;
        #pragma unroll
        for (int rnd = 0; rnd < 2; ++rnd) {
            const float4* W14 = (const float4*)(W1 + (oT*32 + rnd*16)*1024);
            float4* w4 = (float4*)&w[0][0];
            #pragma unroll
            for (int i = 0; i < 8; ++i) w4[t + 512*i] = W14[t + 512*i];
            __syncthreads();
            const int ol = t >> 5, n = t & 31;   // 16 rows x 32 n-lanes
            const float* row = &w[ol][0];
            float T1 = 0.f, T2 = 0.f;
            #pragma unroll
            for (int k = 0; k < 32; ++k) T1 += row[n*32 + ((k + n) & 31)];
            #pragma unroll
            for (int m = 0; m < 32; ++m) T2 += row[m*32 + n];
            float diag = row[n*33];
            st_agent(&W1A[(oT*32 + rnd*16 + ol)*32 + n],
                     (T1 + 2.f*T2 - diag) * (1.f/512.f));
            __syncthreads();
        }
    }
    bar_arrive(&g_bar0[gi]);

    // ---------------- P3b: gram + mask scalars -> regs (hides bar0) --------
    const int ga = t >> 4, gb = t & 15;       // only dereferenced when t<256
    float g00=0.f, g01=0.f, g10=0.f, g11=0.f;
    float sa0=0.f, sa1=0.f, sb0=0.f, sb1=0.f;
    if (t < 256) {
        #pragma unroll 8
        for (int q = 0; q < 64; ++q) {
            float4 a0 = xs4[ga][q],    a1 = xs4[ga+16][q];
            float4 b0 = xs4[gb][q],    b1 = xs4[gb+16][q];
            g00 += dot4(a0,b0); g01 += dot4(a0,b1);
            g10 += dot4(a1,b0); g11 += dot4(a1,b1);
        }
        sa0 = S_loc[ga]    * (1.f/256.f);
        sa1 = S_loc[ga+16] * (1.f/256.f);
        sb0 = S_loc[gb];
        sb1 = S_loc[gb+16];
    }
    bar_wait(&g_bar0[gi]);

    // ---------------- P2: h = relu(W1A@S) + GEMM2 + sigmoid -> Et ----------
    {
        if (t < 256) ((float*)S_l8)[t] = ld_agent(&Ssum[g*256 + t]);
        __syncthreads();
        // h: thread t owns column o=t for all 8 bm rows
        {
            const unsigned long long* wrow =
                (const unsigned long long*)(W1A + t*32);
            float wv[32];
            #pragma unroll
            for (int i = 0; i < 16; ++i) {
                unsigned long long v = ld_agent64(wrow + i);
                wv[2*i]   = __uint_as_float((unsigned)(v & 0xffffffffu));
                wv[2*i+1] = __uint_as_float((unsigned)(v >> 32));
            }
            #pragma unroll
            for (int bl = 0; bl < 8; ++bl) {
                const float* sb = &S_l8[bl][0];    // broadcast reads
                float a = 0.f;
                #pragma unroll
                for (int n = 0; n < 32; ++n) a += wv[n] * sb[n];
                hl[bl][t] = fmaxf(a, 0.f);
            }
        }
        __syncthreads();
        // GEMM2: 64 c's per block (cQ = bid&15), 4 per thread, 32-lane slices
        const int cQ = bid & 15;
        const int olane = t & 31, cgp = t >> 5;
        const int c0 = cQ*64 + cgp;
        const float4* w4a = (const float4*)(W2 + (c0     )*512);
        const float4* w4b = (const float4*)(W2 + (c0 + 16)*512);
        const float4* w4c = (const float4*)(W2 + (c0 + 32)*512);
        const float4* w4d = (const float4*)(W2 + (c0 + 48)*512);
        float accA[8] = {0.f,0.f,0.f,0.f,0.f,0.f,0.f,0.f};
        float accB[8] = {0.f,0.f,0.f,0.f,0.f,0.f,0.f,0.f};
        float accC[8] = {0.f,0.f,0.f,0.f,0.f,0.f,0.f,0.f};
        float accD[8] = {0.f,0.f,0.f,0.f,0.f,0.f,0.f,0.f};
        #pragma unroll
        for (int oo = 0; oo < 4; ++oo) {
            float4 hv[8];
            #pragma unroll
            for (int bl = 0; bl < 8; ++bl)
                hv[bl] = *((const float4*)&hl[bl][(oo*32 + olane)*4]);
            float4 wa = w4a[oo*32 + olane];
            float4 wb = w4b[oo*32 + olane];
            float4 wc = w4c[oo*32 + olane];
            float4 wd = w4d[oo*32 + olane];
            #pragma unroll
            for (int bl = 0; bl < 8; ++bl) {
                accA[bl] += dot4(wa, hv[bl]);
                accB[bl] += dot4(wb, hv[bl]);
                accC[bl] += dot4(wc, hv[bl]);
                accD[bl] += dot4(wd, hv[bl]);
            }
        }
        #pragma unroll
        for (int bl = 0; bl < 8; ++bl) {
            float a = accA[bl], b = accB[bl], c = accC[bl], d = accD[bl];
            #pragma unroll
            for (int m = 1; m < 32; m <<= 1) {
                a += __shfl_xor(a, m, 32);
                b += __shfl_xor(b, m, 32);
                c += __shfl_xor(c, m, 32);
                d += __shfl_xor(d, m, 32);
            }
            accA[bl]=a; accB[bl]=b; accC[bl]=c; accD[bl]=d;
        }
        if (olane == 0) {
            #pragma unroll
            for (int bl = 0; bl < 8; ++bl) {
                int row = (g*8 + bl)*1024;
                st_agent(&Et[row + c0],      1.f/(1.f + __expf(-accA[bl])));
                st_agent(&Et[row + c0 + 16], 1.f/(1.f + __expf(-accB[bl])));
                st_agent(&Et[row + c0 + 32], 1.f/(1.f + __expf(-accC[bl])));
                st_agent(&Et[row + c0 + 48], 1.f/(1.f + __expf(-accD[bl])));
            }
        }
    }
    bar_arrive(&g_bar1[gi]);
    bar_wait(&g_bar1[gi]);

    // ---------------- P3c: mask + softmax + att@x --------------------------
    if (t < 256) {
        const float* Eb = Et + bm*1024;
        float e00 = ld_agent(&Eb[ga*32 + gb]);
        float e01 = ld_agent(&Eb[ga*32 + gb+16]);
        float e10 = ld_agent(&Eb[(ga+16)*32 + gb]);
        float e11 = ld_agent(&Eb[(ga+16)*32 + gb+16]);
        att[ga][gb]       = (g00 - sa0*sb0) > 0.f ? e00 : -1e12f;
        att[ga][gb+16]    = (g01 - sa0*sb1) > 0.f ? e01 : -1e12f;
        att[ga+16][gb]    = (g10 - sa1*sb0) > 0.f ? e10 : -1e12f;
        att[ga+16][gb+16] = (g11 - sa1*sb1) > 0.f ? e11 : -1e12f;
    }
    __syncthreads();
    {
        // masked softmax: 32 rows x 16 lanes, 2 floats per lane
        int r = t >> 4, q = t & 15;
        float2 lg = *((const float2*)&att[r][q*2]);
        float m = fmaxf(lg.x, lg.y);
        m = fmaxf(m, __shfl_xor(m,1,16));
        m = fmaxf(m, __shfl_xor(m,2,16));
        m = fmaxf(m, __shfl_xor(m,4,16));
        m = fmaxf(m, __shfl_xor(m,8,16));
        float2 p;
        p.x = __expf(lg.x-m); p.y = __expf(lg.y-m);
        float s = p.x + p.y;
        s += __shfl_xor(s,1,16);
        s += __shfl_xor(s,2,16);
        s += __shfl_xor(s,4,16);
        s += __shfl_xor(s,8,16);
        float inv = 1.f/s;
        p.x*=inv; p.y*=inv;
        *((float2*)&att[r][q*2]) = p;
    }
    __syncthreads();
    {
        // out[r, d-half] = sum_k att[r,k] * x[k, d-half]; 2 rows per thread
        int txl = t & 31, wy = t >> 5;
        int r0 = wy*2;
        float4 acc0={0,0,0,0}, acc1={0,0,0,0};
        #pragma unroll
        for (int kq = 0; kq < 8; ++kq) {
            float4 xa = xs4[kq*4+0][hh*32 + txl];
            float4 xb = xs4[kq*4+1][hh*32 + txl];
            float4 xc = xs4[kq*4+2][hh*32 + txl];
            float4 xd = xs4[kq*4+3][hh*32 + txl];
            float4 w0 = *((const float4*)&att[r0+0][kq*4]);
            float4 w1 = *((const float4*)&att[r0+1][kq*4]);
            fma4(acc0,w0.x,xa); fma4(acc0,w0.y,xb); fma4(acc0,w0.z,xc); fma4(acc0,w0.w,xd);
            fma4(acc1,w1.x,xa); fma4(acc1,w1.y,xb); fma4(acc1,w1.z,xc); fma4(acc1,w1.w,xd);
        }
        float4* out4 = (float4*)out;
        int base = bm*2048 + hh*32 + txl;
        out4[base + (r0+0)*64] = acc0;
        out4[base + (r0+1)*64] = acc1;
    }

    // ---------------- self-reset of group counters for next launch ---------
    if (t == 0) {
        unsigned int old = __hip_atomic_fetch_add(&g_done[gi], 1u,
                              __ATOMIC_RELAXED, __HIP_MEMORY_SCOPE_AGENT);
        if (old == 15u) {
            __hip_atomic_store(&g_bar0[gi], 0u, __ATOMIC_RELAXED, __HIP_MEMORY_SCOPE_AGENT);
            __hip_atomic_store(&g_bar1[gi], 0u, __ATOMIC_RELAXED, __HIP_MEMORY_SCOPE_AGENT);
            __hip_atomic_store(&g_done[gi], 0u, __ATOMIC_RELAXED, __HIP_MEMORY_SCOPE_AGENT);
        }
    }
}

extern "C" void kernel_launch(void* const* d_in, const int* in_sizes, int n_in,
                              void* d_out, int out_size, void* d_ws, size_t ws_size,
                              hipStream_t stream) {
    const float* x  = (const float*)d_in[0];
    const float* W1 = (const float*)d_in[1];
    const float* W2 = (const float*)d_in[2];
    float* out = (float*)d_out;
    float* ws  = (float*)d_ws;

    float* W1A  = ws;            // 16384 floats
    float* Ssum = ws + 16384;    // 3072 floats
    float* Et   = ws + 19456;    // 98304 floats

    fused<<<192, 512, 0, stream>>>(x, W1, W2, out, W1A, Ssum, Et);
}

// Round 8
// 86.008 us; speedup vs baseline: 1.0293x; 1.0282x over previous
//
#include <hip/hip_runtime.h>

// B=8, M=12, N=32, D=256, C=1024, O=512, BM=96 (b*m rows).
//
// Single normal-launch kernel, grid 192 x 512. r5 algebraic collapse
// (h = relu(W1A @ S)) + r8 d-half split:
//   Block (bm, hh) stages ONLY its 64 KB d-half of x, computes half-D
//   partial gram + half row-sums; partial gram (4 KB) and half-S go to ws.
//   Full S = h0+h1 assembled in P2 (S_l8); full gram assembled after
//   bar1-wait from sibling's partials (visible: sibling stored pg before
//   its bar1-arrive; we read after our bar1-wait).
// Group-scoped arrive/spin barriers (r3/r4/r7-proven), agent-scope data
// movement, zero-init __device__ barrier counters with last-of-16 reset.
//
// Schedule:
//   P0 : stage x-half, half-S -> ws, W1A slice (r7 LDS reduction)
//        -> arrive bar0
//   P3b: half-gram -> regs + pg -> ws (hides bar0)        -> wait bar0
//   P2 : S_l8 = h0+h1; h = relu(W1A@S); GEMM2 + sigmoid -> Et
//        -> arrive bar1 -> wait bar1
//   P3c: gram assembly (sibling pg) + mask(Et) + softmax + att@x -> out
//
// ws (floats): W1A @0 (16384), SsumH @16384 (2x3072), Et @22528 (98304),
//              pg @120832 (192*1024).

#define NGRP 12

__device__ unsigned int g_bar0[NGRP * 32];
__device__ unsigned int g_bar1[NGRP * 32];
__device__ unsigned int g_done[NGRP * 32];

__device__ __forceinline__ float dot4(float4 a, float4 b) {
    return a.x*b.x + a.y*b.y + a.z*b.z + a.w*b.w;
}
__device__ __forceinline__ void fma4(float4& acc, float s, float4 v) {
    acc.x += s*v.x; acc.y += s*v.y; acc.z += s*v.z; acc.w += s*v.w;
}

__device__ __forceinline__ void st_agent(float* p, float v) {
    __hip_atomic_store(p, v, __ATOMIC_RELAXED, __HIP_MEMORY_SCOPE_AGENT);
}
__device__ __forceinline__ float ld_agent(const float* p) {
    return __hip_atomic_load(p, __ATOMIC_RELAXED, __HIP_MEMORY_SCOPE_AGENT);
}
__device__ __forceinline__ unsigned long long ld_agent64(const unsigned long long* p) {
    return __hip_atomic_load(p, __ATOMIC_RELAXED, __HIP_MEMORY_SCOPE_AGENT);
}

// arrive: syncthreads drains all waves' stores (vmcnt 0 at barrier), then +1.
__device__ __forceinline__ void bar_arrive(unsigned int* ctr) {
    __syncthreads();
    if (threadIdx.x == 0)
        __hip_atomic_fetch_add(ctr, 1u, __ATOMIC_RELAXED, __HIP_MEMORY_SCOPE_AGENT);
}
__device__ __forceinline__ void bar_wait(unsigned int* ctr) {
    if (threadIdx.x == 0) {
        while (__hip_atomic_load(ctr, __ATOMIC_RELAXED, __HIP_MEMORY_SCOPE_AGENT) < 16u)
            __builtin_amdgcn_s_sleep(2);
    }
    __syncthreads();
}

__global__ __launch_bounds__(512) void fused(
        const float* __restrict__ x, const float* __restrict__ W1,
        const float* __restrict__ W2, float* __restrict__ out,
        float* __restrict__ W1A, float* __restrict__ SsumH,
        float* __restrict__ Et, float* __restrict__ pg)
{
    __shared__ float4 xs4[32][33];      // 16896 B  (x d-half tile, alive to end)
    __shared__ float  w[16][1024];      // 65536 B  (W1 stage, P0 only)
    __shared__ float  hl[8][512];       // 16384 B  (P2)
    __shared__ float  att[32][36];      //  4608 B  (P3c)
    __shared__ float  S_l8[8][32];      //  1024 B  (P2..P3c, FULL S of group)
    __shared__ float  S_loc[32];        //   128 B  (own-half partial S)
    const int t = threadIdx.x;
    const int bid = blockIdx.x;
    const int g = bid >> 4;             // bm-group 0..11
    const int gi = g * 32;
    const int bm = bid >> 1, hh = bid & 1;
    const int lbl = (bid & 15) >> 1;    // local bm index within group (0..7)
    const float4* x4 = (const float4*)x;

    // ---------------- P0: stage x-half, half-S, W1A slice ------------------
    #pragma unroll
    for (int i = 0; i < 2; ++i) {
        int idx = t + 512*i;            // 0..1023 = 32 rows x 32 f4
        int row = idx >> 5, c4 = idx & 31;
        xs4[row][c4] = x4[bm*2048 + row*64 + hh*32 + c4];
    }
    __syncthreads();
    {
        // own-half row sums: 32 rows x 16 lanes, 2 f4 each
        int r = t >> 4, dq = t & 15;
        float s = 0.f;
        #pragma unroll
        for (int j = 0; j < 2; ++j) {
            float4 v = xs4[r][dq + 16*j];
            s += v.x + v.y + v.z + v.w;
        }
        s += __shfl_xor(s, 1, 16);
        s += __shfl_xor(s, 2, 16);
        s += __shfl_xor(s, 4, 16);
        s += __shfl_xor(s, 8, 16);
        if (dq == 0) S_loc[r] = s;
    }
    __syncthreads();
    if (t < 32) st_agent(&SsumH[hh*3072 + bm*32 + t], S_loc[t]);
    // W1A slice: rows [oT*32, oT*32+32), staged 16 rows at a time (r5/r7)
    {
        const int oT = bid & 15;
        #pragma unroll
        for (int rnd = 0; rnd < 2; ++rnd) {
            const float4* W14 = (const float4*)(W1 + (oT*32 + rnd*16)*1024);
            float4* w4 = (float4*)&w[0][0];
            #pragma unroll
            for (int i = 0; i < 8; ++i) w4[t + 512*i] = W14[t + 512*i];
            __syncthreads();
            const int ol = t >> 5, n = t & 31;   // 16 rows x 32 n-lanes
            const float* row = &w[ol][0];
            float T1 = 0.f, T2 = 0.f;
            #pragma unroll
            for (int k = 0; k < 32; ++k) T1 += row[n*32 + ((k + n) & 31)];
            #pragma unroll
            for (int m = 0; m < 32; ++m) T2 += row[m*32 + n];
            float diag = row[n*33];
            st_agent(&W1A[(oT*32 + rnd*16 + ol)*32 + n],
                     (T1 + 2.f*T2 - diag) * (1.f/512.f));
            __syncthreads();
        }
    }
    bar_arrive(&g_bar0[gi]);

    // ---------------- P3b: half-gram -> regs + pg (hides bar0) -------------
    const int ga = t >> 4, gb = t & 15;       // only dereferenced when t<256
    float g00=0.f, g01=0.f, g10=0.f, g11=0.f;
    if (t < 256) {
        #pragma unroll 8
        for (int q = 0; q < 32; ++q) {        // half-D: 32 f4
            float4 a0 = xs4[ga][q],    a1 = xs4[ga+16][q];
            float4 b0 = xs4[gb][q],    b1 = xs4[gb+16][q];
            g00 += dot4(a0,b0); g01 += dot4(a0,b1);
            g10 += dot4(a1,b0); g11 += dot4(a1,b1);
        }
        float* pgb = pg + bid*1024;
        st_agent(&pgb[ga*32 + gb],          g00);
        st_agent(&pgb[ga*32 + gb+16],       g01);
        st_agent(&pgb[(ga+16)*32 + gb],     g10);
        st_agent(&pgb[(ga+16)*32 + gb+16],  g11);
    }
    bar_wait(&g_bar0[gi]);

    // ---------------- P2: S_l8 = h0+h1; h = relu(W1A@S); GEMM2 -> Et -------
    {
        if (t < 256) {
            int bl = t >> 5, rr = t & 31;
            int o = (g*8 + bl)*32 + rr;
            S_l8[bl][rr] = ld_agent(&SsumH[o]) + ld_agent(&SsumH[3072 + o]);
        }
        __syncthreads();
        // h: thread t owns column o=t for all 8 bm rows
        {
            const unsigned long long* wrow =
                (const unsigned long long*)(W1A + t*32);
            float wv[32];
            #pragma unroll
            for (int i = 0; i < 16; ++i) {
                unsigned long long v = ld_agent64(wrow + i);
                wv[2*i]   = __uint_as_float((unsigned)(v & 0xffffffffu));
                wv[2*i+1] = __uint_as_float((unsigned)(v >> 32));
            }
            #pragma unroll
            for (int bl = 0; bl < 8; ++bl) {
                const float* sb = &S_l8[bl][0];    // broadcast reads
                float a = 0.f;
                #pragma unroll
                for (int n = 0; n < 32; ++n) a += wv[n] * sb[n];
                hl[bl][t] = fmaxf(a, 0.f);
            }
        }
        __syncthreads();
        // GEMM2: 64 c's per block (cQ = bid&15), 4 per thread, 32-lane slices
        const int cQ = bid & 15;
        const int olane = t & 31, cgp = t >> 5;
        const int c0 = cQ*64 + cgp;
        const float4* w4a = (const float4*)(W2 + (c0     )*512);
        const float4* w4b = (const float4*)(W2 + (c0 + 16)*512);
        const float4* w4c = (const float4*)(W2 + (c0 + 32)*512);
        const float4* w4d = (const float4*)(W2 + (c0 + 48)*512);
        float accA[8] = {0.f,0.f,0.f,0.f,0.f,0.f,0.f,0.f};
        float accB[8] = {0.f,0.f,0.f,0.f,0.f,0.f,0.f,0.f};
        float accC[8] = {0.f,0.f,0.f,0.f,0.f,0.f,0.f,0.f};
        float accD[8] = {0.f,0.f,0.f,0.f,0.f,0.f,0.f,0.f};
        #pragma unroll
        for (int oo = 0; oo < 4; ++oo) {
            float4 hv[8];
            #pragma unroll
            for (int bl = 0; bl < 8; ++bl)
                hv[bl] = *((const float4*)&hl[bl][(oo*32 + olane)*4]);
            float4 wa = w4a[oo*32 + olane];
            float4 wb = w4b[oo*32 + olane];
            float4 wc = w4c[oo*32 + olane];
            float4 wd = w4d[oo*32 + olane];
            #pragma unroll
            for (int bl = 0; bl < 8; ++bl) {
                accA[bl] += dot4(wa, hv[bl]);
                accB[bl] += dot4(wb, hv[bl]);
                accC[bl] += dot4(wc, hv[bl]);
                accD[bl] += dot4(wd, hv[bl]);
            }
        }
        #pragma unroll
        for (int bl = 0; bl < 8; ++bl) {
            float a = accA[bl], b = accB[bl], c = accC[bl], d = accD[bl];
            #pragma unroll
            for (int m = 1; m < 32; m <<= 1) {
                a += __shfl_xor(a, m, 32);
                b += __shfl_xor(b, m, 32);
                c += __shfl_xor(c, m, 32);
                d += __shfl_xor(d, m, 32);
            }
            accA[bl]=a; accB[bl]=b; accC[bl]=c; accD[bl]=d;
        }
        if (olane == 0) {
            #pragma unroll
            for (int bl = 0; bl < 8; ++bl) {
                int row = (g*8 + bl)*1024;
                st_agent(&Et[row + c0],      1.f/(1.f + __expf(-accA[bl])));
                st_agent(&Et[row + c0 + 16], 1.f/(1.f + __expf(-accB[bl])));
                st_agent(&Et[row + c0 + 32], 1.f/(1.f + __expf(-accC[bl])));
                st_agent(&Et[row + c0 + 48], 1.f/(1.f + __expf(-accD[bl])));
            }
        }
    }
    bar_arrive(&g_bar1[gi]);
    bar_wait(&g_bar1[gi]);

    // -------- P3c: gram assembly + mask + softmax + att@x ------------------
    if (t < 256) {
        // sibling partial gram (drained before sibling's bar1-arrive)
        const float* pgs = pg + (bid ^ 1)*1024;
        g00 += ld_agent(&pgs[ga*32 + gb]);
        g01 += ld_agent(&pgs[ga*32 + gb+16]);
        g10 += ld_agent(&pgs[(ga+16)*32 + gb]);
        g11 += ld_agent(&pgs[(ga+16)*32 + gb+16]);
        // mask scalars from FULL S (S_l8 assembled in P2)
        float sa0 = S_l8[lbl][ga]    * (1.f/256.f);
        float sa1 = S_l8[lbl][ga+16] * (1.f/256.f);
        float sb0 = S_l8[lbl][gb], sb1 = S_l8[lbl][gb+16];
        const float* Eb = Et + bm*1024;
        float e00 = ld_agent(&Eb[ga*32 + gb]);
        float e01 = ld_agent(&Eb[ga*32 + gb+16]);
        float e10 = ld_agent(&Eb[(ga+16)*32 + gb]);
        float e11 = ld_agent(&Eb[(ga+16)*32 + gb+16]);
        att[ga][gb]       = (g00 - sa0*sb0) > 0.f ? e00 : -1e12f;
        att[ga][gb+16]    = (g01 - sa0*sb1) > 0.f ? e01 : -1e12f;
        att[ga+16][gb]    = (g10 - sa1*sb0) > 0.f ? e10 : -1e12f;
        att[ga+16][gb+16] = (g11 - sa1*sb1) > 0.f ? e11 : -1e12f;
    }
    __syncthreads();
    {
        // masked softmax: 32 rows x 16 lanes, 2 floats per lane
        int r = t >> 4, q = t & 15;
        float2 lg = *((const float2*)&att[r][q*2]);
        float m = fmaxf(lg.x, lg.y);
        m = fmaxf(m, __shfl_xor(m,1,16));
        m = fmaxf(m, __shfl_xor(m,2,16));
        m = fmaxf(m, __shfl_xor(m,4,16));
        m = fmaxf(m, __shfl_xor(m,8,16));
        float2 p;
        p.x = __expf(lg.x-m); p.y = __expf(lg.y-m);
        float s = p.x + p.y;
        s += __shfl_xor(s,1,16);
        s += __shfl_xor(s,2,16);
        s += __shfl_xor(s,4,16);
        s += __shfl_xor(s,8,16);
        float inv = 1.f/s;
        p.x*=inv; p.y*=inv;
        *((float2*)&att[r][q*2]) = p;
    }
    __syncthreads();
    {
        // out[r, own d-half] = sum_k att[r,k] * xhalf[k]; 2 rows per thread
        int txl = t & 31, wy = t >> 5;
        int r0 = wy*2;
        float4 acc0={0,0,0,0}, acc1={0,0,0,0};
        #pragma unroll
        for (int kq = 0; kq < 8; ++kq) {
            float4 xa = xs4[kq*4+0][txl];
            float4 xb = xs4[kq*4+1][txl];
            float4 xc = xs4[kq*4+2][txl];
            float4 xd = xs4[kq*4+3][txl];
            float4 w0 = *((const float4*)&att[r0+0][kq*4]);
            float4 w1 = *((const float4*)&att[r0+1][kq*4]);
            fma4(acc0,w0.x,xa); fma4(acc0,w0.y,xb); fma4(acc0,w0.z,xc); fma4(acc0,w0.w,xd);
            fma4(acc1,w1.x,xa); fma4(acc1,w1.y,xb); fma4(acc1,w1.z,xc); fma4(acc1,w1.w,xd);
        }
        float4* out4 = (float4*)out;
        int base = bm*2048 + hh*32 + txl;
        out4[base + (r0+0)*64] = acc0;
        out4[base + (r0+1)*64] = acc1;
    }

    // ---------------- self-reset of group counters for next launch ---------
    if (t == 0) {
        unsigned int old = __hip_atomic_fetch_add(&g_done[gi], 1u,
                              __ATOMIC_RELAXED, __HIP_MEMORY_SCOPE_AGENT);
        if (old == 15u) {
            __hip_atomic_store(&g_bar0[gi], 0u, __ATOMIC_RELAXED, __HIP_MEMORY_SCOPE_AGENT);
            __hip_atomic_store(&g_bar1[gi], 0u, __ATOMIC_RELAXED, __HIP_MEMORY_SCOPE_AGENT);
            __hip_atomic_store(&g_done[gi], 0u, __ATOMIC_RELAXED, __HIP_MEMORY_SCOPE_AGENT);
        }
    }
}

extern "C" void kernel_launch(void* const* d_in, const int* in_sizes, int n_in,
                              void* d_out, int out_size, void* d_ws, size_t ws_size,
                              hipStream_t stream) {
    const float* x  = (const float*)d_in[0];
    const float* W1 = (const float*)d_in[1];
    const float* W2 = (const float*)d_in[2];
    float* out = (float*)d_out;
    float* ws  = (float*)d_ws;

    float* W1A   = ws;            // 16384 floats
    float* SsumH = ws + 16384;    // 2 x 3072 floats
    float* Et    = ws + 22528;    // 98304 floats
    float* pg    = ws + 120832;   // 192 x 1024 floats

    fused<<<192, 512, 0, stream>>>(x, W1, W2, out, W1A, SsumH, Et, pg);
}